// Round 5
// baseline (229.575 us; speedup 1.0000x reference)
//
#include <hip/hip_runtime.h>

// ---------------------------------------------------------------------------
// QoSNet: gather -> 32-step GRU(D=128) -> batchnorm -> 3x SELU MLP readout
// BS=8192, N_LINKS=512, MAX_LEN=32, D_PATH=128, D_READ=256, N_OUT=3.
// R17 = R16 with two kgru stall-cutters (R16 counters: VALUBusy 42%,
// MfmaUtil 14%, Occ 29% -> latency-bound, not issue-bound):
//   - MFMA operand swap: mfma(W, h, acc) instead of mfma(h, W, acc).
//     A-row/B-col lane layouts are symmetric (row/col = lane&15,
//     k = qd*8+j, both confirmed by the working R16 kernel), so every
//     fragment load is byte-identical; only the C mapping flips: a lane
//     now owns ONE item x 4 consecutive channels.  Epilogue: one packed
//     ds_write_b64 (was 4x b16), one freeze v_cmp (was 4), float4 bias
//     init via MFMA C operand, float4 flow store.
//   - feats register prefetch: load feats(t+2) at loop top, ds_write the
//     value loaded LAST iteration -> the vmcnt wait hides under a full
//     step instead of stalling every wave at the loop head.
// prep_all / kmlp: R16 verbatim.
// Known fixed floor: ~100 us of harness-side timed overhead (43 us of it is
// the 268 MB ws re-poison fill visible in rocprof).
// ---------------------------------------------------------------------------

#define BS 8192
#define NL 512
#define ML 32
#define DP 128
#define DR 256
#define NJOB 512             // 16 items per job
#define ST 172               // LDS row stride (f16) for K=160 + pad

// workspace layout (float offsets into d_ws)
#define OFF_SUM    64
#define OFF_SSQ    192
#define OFF_CUR    576
#define OFF_PERM   640                      // BS ints
#define OFF_WHH16  (OFF_PERM + BS)          // 49152 f16  = 24576 fl
#define OFF_W1     (OFF_WHH16 + 24576)      // 98304 f16  = 49152 fl
#define OFF_W2     (OFF_W1 + 49152)         // 196608 f16 = 98304 fl
#define OFF_FEATS  (OFF_W2 + 98304)         // BS*ML f16x4 = 2 MB
#define OFF_FLOW   (OFF_FEATS + BS*ML*4)    // BS*DP fl

// prep_all role partition (256-thr blocks)
#define FEATS_BLOCKS 1024
#define MAX_BLOCKS   256
#define WPREP_BLOCKS 336     // 344064 f16 elements / (256 thr * 4 per thread)
#define SORT_BID     (FEATS_BLOCKS + MAX_BLOCKS + WPREP_BLOCKS)   // 1616
#define PREP_GRID    (SORT_BID + 1)

#define KS (-1.44269504088896340736f)   // -log2(e): sigmoid arg scale
#define KT ( 2.88539008177792681472f)   //  2*log2(e): tanh arg scale

typedef _Float16 f16x8 __attribute__((ext_vector_type(8)));
typedef _Float16 f16x4 __attribute__((ext_vector_type(4)));
typedef float    f32x4 __attribute__((ext_vector_type(4)));

// gate helpers: args arrive pre-scaled by KS / KT via the weight tables
__device__ __forceinline__ float sig2_(float x){      // x = -log2e * s
  return __builtin_amdgcn_rcpf(1.0f + exp2f(x));
}
__device__ __forceinline__ float tanh2_(float v){     // v = 2*log2e * u
  return fmaf(-2.0f, __builtin_amdgcn_rcpf(1.0f + exp2f(v)), 1.0f);
}
__device__ __forceinline__ float seluf_(float x){
  const float sc = 1.0507009873554805f, al = 1.6732632423543772f;
  return x > 0.0f ? sc*x : sc*al*(__expf(x)-1.0f);
}

// ---------------------------------------------------------------------------
// prep_all: independent roles by blockIdx.x (R16 verbatim).
// ---------------------------------------------------------------------------
__global__ void prep_all(const int* __restrict__ path, const int* __restrict__ hop,
                         const float* __restrict__ avail, const float* __restrict__ capa,
                         const float* __restrict__ loss, const float* __restrict__ whh,
                         const float* __restrict__ rW1, const float* __restrict__ rW2,
                         float* ws){
  const int bid = blockIdx.x;
  const int tid = threadIdx.x;

  if (bid < FEATS_BLOCKS){                       // ---- feats gather (f16x4) ----
    int idx = bid*256 + tid;                     // over BS*ML
    int b = idx >> 5, t = idx & 31;
    f16x4 o = (f16x4)0;
    if (t < hop[b]){
      int l = path[idx];
      float a = avail[b*NL + l];
      float c = capa [b*NL + l];
      o[0] = (_Float16)a;
      o[1] = (_Float16)c;
      o[2] = (_Float16)(a / c);
      o[3] = (_Float16)loss[b*NL + l];
    }
    ((f16x4*)((_Float16*)(ws + OFF_FEATS)))[idx] = o;
  } else if (bid < FEATS_BLOCKS + MAX_BLOCKS){   // ---- global max(capa) ----
    const float4* c4 = (const float4*)capa;
    const int n4 = BS*NL/4;
    float m = 0.0f;
    for (int i = (bid - FEATS_BLOCKS)*256 + tid; i < n4; i += MAX_BLOCKS*256){
      float4 v = c4[i];
      m = fmaxf(m, fmaxf(fmaxf(v.x, v.y), fmaxf(v.z, v.w)));
    }
    #pragma unroll
    for (int o = 32; o > 0; o >>= 1) m = fmaxf(m, __shfl_down(m, o, 64));
    if ((tid & 63) == 0) atomicMax((int*)ws, __float_as_int(m));
  } else if (bid < SORT_BID){                    // ---- f16 weight tables ----
    _Float16* whh16 = (_Float16*)(ws + OFF_WHH16);
    _Float16* w1    = (_Float16*)(ws + OFF_W1);
    _Float16* w2    = (_Float16*)(ws + OFF_W2);
    int base = (bid - FEATS_BLOCKS - MAX_BLOCKS)*1024 + tid*4;
    if (base < 49152){
      // r/z rows (elems < 32768) pre-scaled by -log2e; n rows by 2log2e
      const float s = (base < 32768) ? KS : KT;
      const float4 v = *(const float4*)(whh + base);
      f16x4 o = { (_Float16)(v.x*s), (_Float16)(v.y*s),
                  (_Float16)(v.z*s), (_Float16)(v.w*s) };
      *(f16x4*)(whh16 + base) = o;
    } else if (base < 147456){
      int j = base - 49152; int u = j >> 15; int rem = j & 32767; int n = rem >> 7; int k = rem & 127;
      const float* src = rW1 + u*32768 + k*256 + n;   // k..k+3 same u,n (k%4==0)
      f16x4 o = { (_Float16)src[0], (_Float16)src[256], (_Float16)src[512], (_Float16)src[768] };
      *(f16x4*)(w1 + j) = o;
    } else {
      int j = base - 147456; int u = j >> 16; int rem = j & 65535; int n = rem >> 8; int k = rem & 255;
      const float* src = rW2 + u*65536 + k*256 + n;
      f16x4 o = { (_Float16)src[0], (_Float16)src[256], (_Float16)src[512], (_Float16)src[768] };
      *(f16x4*)(w2 + j) = o;
    }
  } else {                                       // ---- zero ctrl + hop sort ----
    __shared__ int hist[32], start[32];
    for (int i = 64 + tid; i < 640; i += 256) ws[i] = 0.0f;   // SUM/SSQ/CUR
    if (tid < 32) hist[tid] = 0;
    __syncthreads();
    for (int b = tid; b < BS; b += 256) atomicAdd(&hist[32 - hop[b]], 1);  // desc key
    __syncthreads();
    if (tid == 0){ int acc = 0; for (int i = 0; i < 32; ++i){ start[i] = acc; acc += hist[i]; } }
    __syncthreads();
    int* perm = (int*)ws + OFF_PERM;
    for (int b = tid; b < BS; b += 256){
      int pos = atomicAdd(&start[32 - hop[b]], 1);
      perm[pos] = b;
    }
  }
}

// ---------------------------------------------------------------------------
// GRU via MFMA, K=160 augmented A (cols 0..127 h, 128..131 feats, rest 0).
// R17 mapping: W is the MFMA A-operand (row = gate-ch = lane&15 within the
// wave's 16-ch slice), h/feats the B-operand (col = item = lane&15,
// k = qd*8+j) -- fragment loads identical to R16, output transposed so a
// lane owns ONE item x 4 consecutive channels (rows qd*4+r).
// Block = 512 thr = 8 waves = one 16-item hop-uniform job; wave owns 16 ch.
// Static LPT pairing: blocks i and 767-bid share a CU -> jobs i and 511-i.
// ---------------------------------------------------------------------------
__launch_bounds__(512, 4)
__global__ void kgru(const float* __restrict__ demand, const int* __restrict__ hop,
                     const float* __restrict__ wih, const float* __restrict__ bih,
                     const float* __restrict__ bhh, float* __restrict__ ws,
                     float* __restrict__ flow){
  __shared__ _Float16 hA[2][16*ST];
  const int tid  = threadIdx.x;
  const int w    = tid >> 6;          // 0..7
  const int lane = tid & 63;
  const int lm   = lane & 15;         // item index (B col) / weight row (A row)
  const int qd   = lane >> 4;
  const int chw  = w*16 + lm;         // gate-ch for weight fragment loads
  const int cho  = w*16 + qd*4;       // first of this lane's 4 output channels
  const float inv_maxc = 1.0f / ws[0];
  const int* perm = (const int*)ws + OFF_PERM;
  const f16x4* feats16 = (const f16x4*)((const _Float16*)(ws + OFF_FEATS));
  const _Float16* whh16 = (const _Float16*)(ws + OFF_WHH16);

  const int bid = blockIdx.x;
  const int q = (bid < 256) ? bid : 767 - bid;   // LPT pair on shared CU

  // zero pad/feature cols 128..159, both buffers, before any feature write
  for (int idx = tid; idx < 1024; idx += 512){
    const int buf = idx >> 9;
    const int rem = idx & 511;
    const int m   = rem >> 5;
    const int c   = 128 + (rem & 31);
    hA[buf][m*ST + c] = (_Float16)0.f;
  }

  // W~ fragments (register-resident, pre-scaled via whh16 table) -- A-operand
  f16x8 bfr[5], bfz[5], bfnh[4], bfni;
  #pragma unroll
  for (int kc = 0; kc < 4; ++kc){
    bfr[kc]  = *(const f16x8*)(whh16 + (      chw)*128 + kc*32 + qd*8);
    bfz[kc]  = *(const f16x8*)(whh16 + (128 + chw)*128 + kc*32 + qd*8);
    bfnh[kc] = *(const f16x8*)(whh16 + (256 + chw)*128 + kc*32 + qd*8);
  }
  bfr[4] = (f16x8)0; bfz[4] = (f16x8)0; bfni = (f16x8)0;
  if (qd == 0){
    #pragma unroll
    for (int j = 0; j < 4; ++j){
      float s = (j < 2) ? inv_maxc : 1.0f;
      bfr[4][j] = (_Float16)(wih[(      chw)*32 + 28 + j] * s * KS);
      bfz[4][j] = (_Float16)(wih[(128 + chw)*32 + 28 + j] * s * KS);
      bfni[j]   = (_Float16)(wih[(256 + chw)*32 + 28 + j] * s * KT);
    }
  }
  // biases for this lane's 4 output channels (ride in MFMA C operand)
  const float4 biR = *(const float4*)(bih + cho);
  const float4 bhR = *(const float4*)(bhh + cho);
  const float4 biZ = *(const float4*)(bih + 128 + cho);
  const float4 bhZ = *(const float4*)(bhh + 128 + cho);
  const float4 biN = *(const float4*)(bih + 256 + cho);
  const float4 bhN = *(const float4*)(bhh + 256 + cho);
  const f32x4 cR  = { (biR.x+bhR.x)*KS, (biR.y+bhR.y)*KS,
                      (biR.z+bhR.z)*KS, (biR.w+bhR.w)*KS };
  const f32x4 cZ  = { (biZ.x+bhZ.x)*KS, (biZ.y+bhZ.y)*KS,
                      (biZ.z+bhZ.z)*KS, (biZ.w+bhZ.w)*KS };
  const f32x4 cNI = { biN.x*KT, biN.y*KT, biN.z*KT, biN.w*KT };
  const f32x4 cNH = { bhN.x*KT, bhN.y*KT, bhN.z*KT, bhN.w*KT };

  // job item owned by this lane (same 16 items seen by every wave)
  const int it = perm[q*16 + lm];
  const int hp = hop[it];
  int tmax = hp;
  tmax = max(tmax, __shfl_xor(tmax, 1, 64));
  tmax = max(tmax, __shfl_xor(tmax, 2, 64));
  tmax = max(tmax, __shfl_xor(tmax, 4, 64));
  tmax = max(tmax, __shfl_xor(tmax, 8, 64));

  // feature-writer lanes: 2 per wave (item = w*2 + lane, one f16x4 each)
  const int  fw_i = w*2 + lane;
  const bool fw   = (lane < 2);
  const int  fw_b = fw ? perm[q*16 + fw_i] : 0;

  __syncthreads();   // pad zeroing complete before feature writes

  // init: h0 (lane's 4 channels of its item) + features(t=0) + prefetch t=1
  float hprev[4] = {0.f, 0.f, 0.f, 0.f};
  if (w == 7 && qd == 3) hprev[3] = demand[it] * inv_maxc;   // ch 127
  {
    f16x4 pk = { (_Float16)hprev[0], (_Float16)hprev[1],
                 (_Float16)hprev[2], (_Float16)hprev[3] };
    *(f16x4*)(&hA[0][lm*ST + cho]) = pk;
  }
  f16x4 fvreg = (f16x4)0;
  if (fw){
    *(f16x4*)(&hA[0][fw_i*ST + 128]) = feats16[fw_b*ML + 0];
    fvreg = feats16[fw_b*ML + 1];
  }
  __syncthreads();

  for (int t = 0; t < tmax; ++t){
    const int cur = t & 1, nxt = cur ^ 1;

    f16x4 fvnext = fvreg;
    if (fw){
      *(f16x4*)(&hA[nxt][fw_i*ST + 128]) = fvreg;   // feats(t+1), loaded last iter
      int tn = t + 2; tn = (tn < ML) ? tn : (ML - 1);
      fvnext = feats16[fw_b*ML + tn];               // in flight across this step
    }

    // biases ride in the MFMA C operand (D = A*B + C), pre-scaled
    f32x4 accr = cR, accz = cZ, accnh = cNH, accni = cNI;
    #pragma unroll
    for (int kc = 0; kc < 5; ++kc){
      f16x8 a = *(const f16x8*)(&hA[cur][lm*ST + kc*32 + qd*8]);
      accr = __builtin_amdgcn_mfma_f32_16x16x32_f16(bfr[kc], a, accr, 0, 0, 0);
      accz = __builtin_amdgcn_mfma_f32_16x16x32_f16(bfz[kc], a, accz, 0, 0, 0);
      if (kc < 4)
        accnh = __builtin_amdgcn_mfma_f32_16x16x32_f16(bfnh[kc], a, accnh, 0, 0, 0);
      else
        accni = __builtin_amdgcn_mfma_f32_16x16x32_f16(bfni, a, accni, 0, 0, 0);
    }

    const bool upd = (t < hp);      // one freeze test per lane (item-uniform)
    f16x4 pk;
    #pragma unroll
    for (int r = 0; r < 4; ++r){
      float rr = sig2_(accr[r]);
      float zz = sig2_(accz[r]);
      float nn = tanh2_(fmaf(rr, accnh[r], accni[r]));
      float hn = fmaf(zz, hprev[r] - nn, nn);          // (1-z)*n + z*h
      if (upd) hprev[r] = hn;
      pk[r] = (_Float16)hprev[r];
    }
    *(f16x4*)(&hA[nxt][lm*ST + cho]) = pk;             // one b64 write
    fvreg = fvnext;
    __syncthreads();
  }

  // flow write (float4, lane's item x 4 ch) + BN partials (reduce over items)
  {
    float4 fo = { hprev[0], hprev[1], hprev[2], hprev[3] };
    *(float4*)(&flow[it*DP + cho]) = fo;
  }
  float sv0 = hprev[0], sv1 = hprev[1], sv2 = hprev[2], sv3 = hprev[3];
  float qv0 = hprev[0]*hprev[0], qv1 = hprev[1]*hprev[1];
  float qv2 = hprev[2]*hprev[2], qv3 = hprev[3]*hprev[3];
  #pragma unroll
  for (int o = 1; o < 16; o <<= 1){
    sv0 += __shfl_xor(sv0, o, 64);  qv0 += __shfl_xor(qv0, o, 64);
    sv1 += __shfl_xor(sv1, o, 64);  qv1 += __shfl_xor(qv1, o, 64);
    sv2 += __shfl_xor(sv2, o, 64);  qv2 += __shfl_xor(qv2, o, 64);
    sv3 += __shfl_xor(sv3, o, 64);  qv3 += __shfl_xor(qv3, o, 64);
  }
  if (lm == 0){
    atomicAdd(&ws[OFF_SUM + cho + 0], sv0);
    atomicAdd(&ws[OFF_SUM + cho + 1], sv1);
    atomicAdd(&ws[OFF_SUM + cho + 2], sv2);
    atomicAdd(&ws[OFF_SUM + cho + 3], sv3);
    atomicAdd(&ws[OFF_SSQ + cho + 0], qv0);
    atomicAdd(&ws[OFF_SSQ + cho + 1], qv1);
    atomicAdd(&ws[OFF_SSQ + cho + 2], qv2);
    atomicAdd(&ws[OFF_SSQ + cho + 3], qv3);
  }
}

// ---------------------------------------------------------------------------
// BN-finalize + 3-headed MLP via MFMA (R10 verbatim).
// ---------------------------------------------------------------------------
__launch_bounds__(256, 4)
__global__ void kmlp(const float* __restrict__ flow, const float* __restrict__ ws,
                     const float* __restrict__ gamma, const float* __restrict__ beta,
                     const float* __restrict__ rb1, const float* __restrict__ rb2,
                     const float* __restrict__ rW3, const float* __restrict__ rb3,
                     float* __restrict__ out){
  __shared__ _Float16 x_lds[32*136];
  __shared__ _Float16 h1_lds[32*264];
  __shared__ float aa[DP], bb[DP];
  __shared__ float y_part[4][32];
  const int tid  = threadIdx.x;
  const int w    = tid >> 6;
  const int lane = tid & 63;
  const int lm   = lane & 15;
  const int qd   = lane >> 4;
  const int b0   = blockIdx.x * 32;
  const int u    = blockIdx.y;
  const _Float16* w1 = (const _Float16*)(ws + OFF_W1) + u*(DR*DP);
  const _Float16* w2 = (const _Float16*)(ws + OFF_W2) + u*(DR*DR);

  if (tid < DP){                                // BN finalize (redundant/block)
    float m = ws[OFF_SUM + tid] * (1.0f/BS);
    float q = ws[OFF_SSQ + tid] * (1.0f/BS);
    float rstd = rsqrtf(q - m*m + 1e-5f);
    float a = rstd * gamma[tid];
    aa[tid] = a;
    bb[tid] = fmaf(-m, a, beta[tid]);
  }
  __syncthreads();

  for (int idx = tid; idx < 32*DP; idx += 256){
    int i = idx >> 7, h = idx & 127;
    x_lds[i*136 + h] = (_Float16)fmaf(flow[(b0 + i)*DP + h], aa[h], bb[h]);
  }
  __syncthreads();

  // ---- L1: 32x128 @ 128x256 -> selu -> h1_lds ----
  for (int nt = 0; nt < 4; ++nt){
    const int n = (4*w + nt)*16 + lm;
    const float bias1 = rb1[u*DR + n];
    f16x8 b1[4];
    #pragma unroll
    for (int kc = 0; kc < 4; ++kc)
      b1[kc] = *(const f16x8*)(w1 + n*DP + kc*32 + qd*8);
    #pragma unroll
    for (int mt = 0; mt < 2; ++mt){
      f32x4 acc = {bias1, bias1, bias1, bias1};
      #pragma unroll
      for (int kc = 0; kc < 4; ++kc){
        f16x8 a1 = *(const f16x8*)(&x_lds[(mt*16 + lm)*136 + kc*32 + qd*8]);
        acc = __builtin_amdgcn_mfma_f32_16x16x32_f16(a1, b1[kc], acc, 0, 0, 0);
      }
      #pragma unroll
      for (int r = 0; r < 4; ++r)
        h1_lds[(mt*16 + qd*4 + r)*264 + n] = (_Float16)seluf_(acc[r]);
    }
  }
  __syncthreads();

  // ---- L2: 32x256 @ 256x256 -> selu -> dot w3 (in-wave reduce) ----
  {
    float p[2][4] = {{0.f,0.f,0.f,0.f},{0.f,0.f,0.f,0.f}};
    for (int nt = 0; nt < 4; ++nt){
      const int n = (4*w + nt)*16 + lm;
      const float bias2 = rb2[u*DR + n];
      const float w3l   = rW3[u*DR + n];
      f16x8 b2[8];
      #pragma unroll
      for (int kc = 0; kc < 8; ++kc)
        b2[kc] = *(const f16x8*)(w2 + n*DR + kc*32 + qd*8);
      #pragma unroll
      for (int mt = 0; mt < 2; ++mt){
        f32x4 acc = {bias2, bias2, bias2, bias2};
        #pragma unroll
        for (int kc = 0; kc < 8; ++kc){
          f16x8 a2 = *(const f16x8*)(&h1_lds[(mt*16 + lm)*264 + kc*32 + qd*8]);
          acc = __builtin_amdgcn_mfma_f32_16x16x32_f16(a2, b2[kc], acc, 0, 0, 0);
        }
        #pragma unroll
        for (int r = 0; r < 4; ++r)
          p[mt][r] += seluf_(acc[r]) * w3l;
      }
    }
    #pragma unroll
    for (int mt = 0; mt < 2; ++mt){
      #pragma unroll
      for (int r = 0; r < 4; ++r){
        float v = p[mt][r];
        v += __shfl_xor(v, 1, 64);
        v += __shfl_xor(v, 2, 64);
        v += __shfl_xor(v, 4, 64);
        v += __shfl_xor(v, 8, 64);
        if (lm == 0) y_part[w][mt*16 + qd*4 + r] = v;
      }
    }
  }
  __syncthreads();
  if (tid < 32){
    float y = y_part[0][tid] + y_part[1][tid] + y_part[2][tid] + y_part[3][tid] + rb3[u];
    out[(b0 + tid)*3 + u] = y;
  }
}

extern "C" void kernel_launch(void* const* d_in, const int* in_sizes, int n_in,
                              void* d_out, int out_size, void* d_ws, size_t ws_size,
                              hipStream_t stream){
  const float* demand = (const float*)d_in[0];
  const float* avail  = (const float*)d_in[1];
  const float* capa   = (const float*)d_in[2];
  const float* loss   = (const float*)d_in[3];
  const int*   path   = (const int*)d_in[4];
  const int*   hop    = (const int*)d_in[5];
  const float* wih    = (const float*)d_in[6];
  const float* whh    = (const float*)d_in[7];
  const float* bih    = (const float*)d_in[8];
  const float* bhh    = (const float*)d_in[9];
  const float* gamma  = (const float*)d_in[10];
  const float* beta   = (const float*)d_in[11];
  const float* rW1    = (const float*)d_in[12];
  const float* rb1    = (const float*)d_in[13];
  const float* rW2    = (const float*)d_in[14];
  const float* rb2    = (const float*)d_in[15];
  const float* rW3    = (const float*)d_in[16];
  const float* rb3    = (const float*)d_in[17];
  float* ws  = (float*)d_ws;
  float* out = (float*)d_out;

  prep_all <<<PREP_GRID, 256, 0, stream>>>(path, hop, avail, capa, loss,
                                           whh, rW1, rW2, ws);
  kgru     <<<NJOB, 512, 0, stream>>>(demand, hop, wih, bih, bhh, ws, ws + OFF_FLOW);
  kmlp     <<<dim3(BS/32, 3), 256, 0, stream>>>(ws + OFF_FLOW, ws, gamma, beta,
                                                rb1, rb2, rW3, rb3, out);
}

// Round 6
// 206.469 us; speedup vs baseline: 1.1119x; 1.1119x over previous
//
#include <hip/hip_runtime.h>

// ---------------------------------------------------------------------------
// QoSNet: gather -> 32-step GRU(D=128) -> batchnorm -> 3x SELU MLP readout
// BS=8192, N_LINKS=512, MAX_LEN=32, D_PATH=128, D_READ=256, N_OUT=3.
// R18 = R16 + ONE isolated change (R17 bundled two and regressed 200->230;
// the MFMA operand swap is the prime suspect and is reverted for good):
//   - feats register prefetch in kgru: at step t, ds_write the f16x4 value
//     loaded at step t-1 and issue the load for t+2.  Removes the
//     s_waitcnt vmcnt(0) that sat between the feats load and its ds_write
//     at the top of every step (L2 ~200cy x 33 steps serial per block).
// Everything else (R16 = R13 structure + exp2-folded gates + packed f16x4
// feats): byte-identical.  prep_all / kmlp: R16 verbatim.
// Known fixed floor: ~100 us of harness-side timed overhead (43 us of it is
// the 268 MB ws re-poison fill visible in rocprof).
// ---------------------------------------------------------------------------

#define BS 8192
#define NL 512
#define ML 32
#define DP 128
#define DR 256
#define NJOB 512             // 16 items per job
#define ST 172               // LDS row stride (f16) for K=160 + pad

// workspace layout (float offsets into d_ws)
#define OFF_SUM    64
#define OFF_SSQ    192
#define OFF_CUR    576
#define OFF_PERM   640                      // BS ints
#define OFF_WHH16  (OFF_PERM + BS)          // 49152 f16  = 24576 fl
#define OFF_W1     (OFF_WHH16 + 24576)      // 98304 f16  = 49152 fl
#define OFF_W2     (OFF_W1 + 49152)         // 196608 f16 = 98304 fl
#define OFF_FEATS  (OFF_W2 + 98304)         // BS*ML f16x4 = 2 MB
#define OFF_FLOW   (OFF_FEATS + BS*ML*4)    // BS*DP fl

// prep_all role partition (256-thr blocks)
#define FEATS_BLOCKS 1024
#define MAX_BLOCKS   256
#define WPREP_BLOCKS 336     // 344064 f16 elements / (256 thr * 4 per thread)
#define SORT_BID     (FEATS_BLOCKS + MAX_BLOCKS + WPREP_BLOCKS)   // 1616
#define PREP_GRID    (SORT_BID + 1)

#define KS (-1.44269504088896340736f)   // -log2(e): sigmoid arg scale
#define KT ( 2.88539008177792681472f)   //  2*log2(e): tanh arg scale

typedef _Float16 f16x8 __attribute__((ext_vector_type(8)));
typedef _Float16 f16x4 __attribute__((ext_vector_type(4)));
typedef float    f32x4 __attribute__((ext_vector_type(4)));

// gate helpers: args arrive pre-scaled by KS / KT via the weight tables
__device__ __forceinline__ float sig2_(float x){      // x = -log2e * s
  return __builtin_amdgcn_rcpf(1.0f + exp2f(x));
}
__device__ __forceinline__ float tanh2_(float v){     // v = 2*log2e * u
  return fmaf(-2.0f, __builtin_amdgcn_rcpf(1.0f + exp2f(v)), 1.0f);
}
__device__ __forceinline__ float seluf_(float x){
  const float sc = 1.0507009873554805f, al = 1.6732632423543772f;
  return x > 0.0f ? sc*x : sc*al*(__expf(x)-1.0f);
}

// ---------------------------------------------------------------------------
// prep_all: independent roles by blockIdx.x (R16 verbatim).
// ---------------------------------------------------------------------------
__global__ void prep_all(const int* __restrict__ path, const int* __restrict__ hop,
                         const float* __restrict__ avail, const float* __restrict__ capa,
                         const float* __restrict__ loss, const float* __restrict__ whh,
                         const float* __restrict__ rW1, const float* __restrict__ rW2,
                         float* ws){
  const int bid = blockIdx.x;
  const int tid = threadIdx.x;

  if (bid < FEATS_BLOCKS){                       // ---- feats gather (f16x4) ----
    int idx = bid*256 + tid;                     // over BS*ML
    int b = idx >> 5, t = idx & 31;
    f16x4 o = (f16x4)0;
    if (t < hop[b]){
      int l = path[idx];
      float a = avail[b*NL + l];
      float c = capa [b*NL + l];
      o[0] = (_Float16)a;
      o[1] = (_Float16)c;
      o[2] = (_Float16)(a / c);
      o[3] = (_Float16)loss[b*NL + l];
    }
    ((f16x4*)((_Float16*)(ws + OFF_FEATS)))[idx] = o;
  } else if (bid < FEATS_BLOCKS + MAX_BLOCKS){   // ---- global max(capa) ----
    const float4* c4 = (const float4*)capa;
    const int n4 = BS*NL/4;
    float m = 0.0f;
    for (int i = (bid - FEATS_BLOCKS)*256 + tid; i < n4; i += MAX_BLOCKS*256){
      float4 v = c4[i];
      m = fmaxf(m, fmaxf(fmaxf(v.x, v.y), fmaxf(v.z, v.w)));
    }
    #pragma unroll
    for (int o = 32; o > 0; o >>= 1) m = fmaxf(m, __shfl_down(m, o, 64));
    if ((tid & 63) == 0) atomicMax((int*)ws, __float_as_int(m));
  } else if (bid < SORT_BID){                    // ---- f16 weight tables ----
    _Float16* whh16 = (_Float16*)(ws + OFF_WHH16);
    _Float16* w1    = (_Float16*)(ws + OFF_W1);
    _Float16* w2    = (_Float16*)(ws + OFF_W2);
    int base = (bid - FEATS_BLOCKS - MAX_BLOCKS)*1024 + tid*4;
    if (base < 49152){
      // r/z rows (elems < 32768) pre-scaled by -log2e; n rows by 2log2e
      const float s = (base < 32768) ? KS : KT;
      const float4 v = *(const float4*)(whh + base);
      f16x4 o = { (_Float16)(v.x*s), (_Float16)(v.y*s),
                  (_Float16)(v.z*s), (_Float16)(v.w*s) };
      *(f16x4*)(whh16 + base) = o;
    } else if (base < 147456){
      int j = base - 49152; int u = j >> 15; int rem = j & 32767; int n = rem >> 7; int k = rem & 127;
      const float* src = rW1 + u*32768 + k*256 + n;   // k..k+3 same u,n (k%4==0)
      f16x4 o = { (_Float16)src[0], (_Float16)src[256], (_Float16)src[512], (_Float16)src[768] };
      *(f16x4*)(w1 + j) = o;
    } else {
      int j = base - 147456; int u = j >> 16; int rem = j & 65535; int n = rem >> 8; int k = rem & 255;
      const float* src = rW2 + u*65536 + k*256 + n;
      f16x4 o = { (_Float16)src[0], (_Float16)src[256], (_Float16)src[512], (_Float16)src[768] };
      *(f16x4*)(w2 + j) = o;
    }
  } else {                                       // ---- zero ctrl + hop sort ----
    __shared__ int hist[32], start[32];
    for (int i = 64 + tid; i < 640; i += 256) ws[i] = 0.0f;   // SUM/SSQ/CUR
    if (tid < 32) hist[tid] = 0;
    __syncthreads();
    for (int b = tid; b < BS; b += 256) atomicAdd(&hist[32 - hop[b]], 1);  // desc key
    __syncthreads();
    if (tid == 0){ int acc = 0; for (int i = 0; i < 32; ++i){ start[i] = acc; acc += hist[i]; } }
    __syncthreads();
    int* perm = (int*)ws + OFF_PERM;
    for (int b = tid; b < BS; b += 256){
      int pos = atomicAdd(&start[32 - hop[b]], 1);
      perm[pos] = b;
    }
  }
}

// ---------------------------------------------------------------------------
// GRU via MFMA, K=160 augmented A (cols 0..127 h, 128..131 feats, rest 0).
// Single-f16 h: accr/accz get 5 MFMAs, accnh 4, accni 1 per wave per step.
// Block = 512 thr = 8 waves = one 16-item hop-uniform job; wave owns 16 ch.
// Static LPT pairing: blocks i and 767-bid share a CU -> jobs i and 511-i.
// R18: feats f16x4 register prefetch (load t+2, write value from t-1) so the
// vmcnt wait retires under a full step instead of stalling the loop head.
// ---------------------------------------------------------------------------
__launch_bounds__(512, 4)
__global__ void kgru(const float* __restrict__ demand, const int* __restrict__ hop,
                     const float* __restrict__ wih, const float* __restrict__ bih,
                     const float* __restrict__ bhh, float* __restrict__ ws,
                     float* __restrict__ flow){
  __shared__ _Float16 hA[2][16*ST];
  const int tid  = threadIdx.x;
  const int w    = tid >> 6;          // 0..7
  const int lane = tid & 63;
  const int lm   = lane & 15;
  const int qd   = lane >> 4;
  const int ch   = w*16 + lm;         // channel owned
  const float inv_maxc = 1.0f / ws[0];
  const int* perm = (const int*)ws + OFF_PERM;
  const f16x4* feats16 = (const f16x4*)((const _Float16*)(ws + OFF_FEATS));
  const _Float16* whh16 = (const _Float16*)(ws + OFF_WHH16);

  const int bid = blockIdx.x;
  const int q = (bid < 256) ? bid : 767 - bid;   // LPT pair on shared CU

  // zero pad/feature cols 128..159, both buffers, before any feature write
  for (int idx = tid; idx < 1024; idx += 512){
    const int buf = idx >> 9;
    const int rem = idx & 511;
    const int m   = rem >> 5;
    const int c   = 128 + (rem & 31);
    hA[buf][m*ST + c] = (_Float16)0.f;
  }

  // B~ fragments (register-resident, pre-scaled via whh16 table)
  f16x8 bfr[5], bfz[5], bfnh[4], bfni;
  #pragma unroll
  for (int kc = 0; kc < 4; ++kc){
    bfr[kc]  = *(const f16x8*)(whh16 + (      ch)*128 + kc*32 + qd*8);
    bfz[kc]  = *(const f16x8*)(whh16 + (128 + ch)*128 + kc*32 + qd*8);
    bfnh[kc] = *(const f16x8*)(whh16 + (256 + ch)*128 + kc*32 + qd*8);
  }
  bfr[4] = (f16x8)0; bfz[4] = (f16x8)0; bfni = (f16x8)0;
  if (qd == 0){
    #pragma unroll
    for (int j = 0; j < 4; ++j){
      float s = (j < 2) ? inv_maxc : 1.0f;
      bfr[4][j] = (_Float16)(wih[(      ch)*32 + 28 + j] * s * KS);
      bfz[4][j] = (_Float16)(wih[(128 + ch)*32 + 28 + j] * s * KS);
      bfni[j]   = (_Float16)(wih[(256 + ch)*32 + 28 + j] * s * KT);
    }
  }
  const float bR  = (bih[ch]     + bhh[ch]    ) * KS;
  const float bZ  = (bih[128+ch] + bhh[128+ch]) * KS;
  const float bNI = bih[256+ch] * KT;
  const float bNH = bhh[256+ch] * KT;

  // job items (per quad: 4 items)
  int it[4], hp[4];
  #pragma unroll
  for (int r = 0; r < 4; ++r){
    it[r] = perm[q*16 + qd*4 + r];
    hp[r] = hop[it[r]];
  }
  int tmax = max(max(hp[0],hp[1]), max(hp[2],hp[3]));
  tmax = max(tmax, __shfl_xor(tmax, 16, 64));
  tmax = max(tmax, __shfl_xor(tmax, 32, 64));

  // feature-writer lanes: 2 per wave (item = w*2 + lane, one f16x4 each)
  const int  fw_i = w*2 + lane;
  const bool fw   = (lane < 2);
  const int  fw_b = fw ? perm[q*16 + fw_i] : 0;

  __syncthreads();   // pad zeroing complete before feature writes

  // init: h0 (cols 0..127) + features(t=0); prime the feats pipeline
  float hprev[4];
  #pragma unroll
  for (int r = 0; r < 4; ++r){
    float h0 = (ch == 127) ? demand[it[r]] * inv_maxc : 0.0f;
    hprev[r] = h0;
    hA[0][(qd*4 + r)*ST + ch] = (_Float16)h0;
  }
  f16x4 fvreg = (f16x4)0;
  if (fw){
    *(f16x4*)(&hA[0][fw_i*ST + 128]) = feats16[fw_b*ML + 0];
    fvreg = feats16[fw_b*ML + 1];     // feats(t=1), retires during step 0
  }
  __syncthreads();

  for (int t = 0; t < tmax; ++t){
    const int cur = t & 1, nxt = cur ^ 1;
    if (fw){
      *(f16x4*)(&hA[nxt][fw_i*ST + 128]) = fvreg;   // feats(t+1), loaded at t-1
      int tn = t + 2; tn = (tn < ML) ? tn : (ML - 1);
      fvreg = feats16[fw_b*ML + tn];                // in flight across this step
    }

    // biases ride in the MFMA C operand (D = A*B + C), pre-scaled
    f32x4 accr  = {bR, bR, bR, bR};
    f32x4 accz  = {bZ, bZ, bZ, bZ};
    f32x4 accnh = {bNH, bNH, bNH, bNH};
    f32x4 accni = {bNI, bNI, bNI, bNI};
    #pragma unroll
    for (int kc = 0; kc < 5; ++kc){
      f16x8 a = *(const f16x8*)(&hA[cur][lm*ST + kc*32 + qd*8]);
      accr = __builtin_amdgcn_mfma_f32_16x16x32_f16(a, bfr[kc], accr, 0, 0, 0);
      accz = __builtin_amdgcn_mfma_f32_16x16x32_f16(a, bfz[kc], accz, 0, 0, 0);
      if (kc < 4)
        accnh = __builtin_amdgcn_mfma_f32_16x16x32_f16(a, bfnh[kc], accnh, 0, 0, 0);
      else
        accni = __builtin_amdgcn_mfma_f32_16x16x32_f16(a, bfni, accni, 0, 0, 0);
    }

    #pragma unroll
    for (int r = 0; r < 4; ++r){
      float rr = sig2_(accr[r]);
      float zz = sig2_(accz[r]);
      float nn = tanh2_(fmaf(rr, accnh[r], accni[r]));
      float hn = fmaf(zz, hprev[r] - nn, nn);          // (1-z)*n + z*h
      if (t < hp[r]) hprev[r] = hn;                    // freeze finished items
      hA[nxt][(qd*4 + r)*ST + ch] = (_Float16)hprev[r];
    }
    __syncthreads();
  }

  float ssum = 0.f, ssq = 0.f;
  #pragma unroll
  for (int r = 0; r < 4; ++r){
    float v = hprev[r];
    flow[it[r]*DP + ch] = v;
    ssum += v;
    ssq  = fmaf(v, v, ssq);
  }
  ssum += __shfl_xor(ssum, 16, 64);  ssum += __shfl_xor(ssum, 32, 64);
  ssq  += __shfl_xor(ssq,  16, 64);  ssq  += __shfl_xor(ssq,  32, 64);
  if (qd == 0){
    atomicAdd(&ws[OFF_SUM + ch], ssum);
    atomicAdd(&ws[OFF_SSQ + ch], ssq);
  }
}

// ---------------------------------------------------------------------------
// BN-finalize + 3-headed MLP via MFMA (R10 verbatim).
// ---------------------------------------------------------------------------
__launch_bounds__(256, 4)
__global__ void kmlp(const float* __restrict__ flow, const float* __restrict__ ws,
                     const float* __restrict__ gamma, const float* __restrict__ beta,
                     const float* __restrict__ rb1, const float* __restrict__ rb2,
                     const float* __restrict__ rW3, const float* __restrict__ rb3,
                     float* __restrict__ out){
  __shared__ _Float16 x_lds[32*136];
  __shared__ _Float16 h1_lds[32*264];
  __shared__ float aa[DP], bb[DP];
  __shared__ float y_part[4][32];
  const int tid  = threadIdx.x;
  const int w    = tid >> 6;
  const int lane = tid & 63;
  const int lm   = lane & 15;
  const int qd   = lane >> 4;
  const int b0   = blockIdx.x * 32;
  const int u    = blockIdx.y;
  const _Float16* w1 = (const _Float16*)(ws + OFF_W1) + u*(DR*DP);
  const _Float16* w2 = (const _Float16*)(ws + OFF_W2) + u*(DR*DR);

  if (tid < DP){                                // BN finalize (redundant/block)
    float m = ws[OFF_SUM + tid] * (1.0f/BS);
    float q = ws[OFF_SSQ + tid] * (1.0f/BS);
    float rstd = rsqrtf(q - m*m + 1e-5f);
    float a = rstd * gamma[tid];
    aa[tid] = a;
    bb[tid] = fmaf(-m, a, beta[tid]);
  }
  __syncthreads();

  for (int idx = tid; idx < 32*DP; idx += 256){
    int i = idx >> 7, h = idx & 127;
    x_lds[i*136 + h] = (_Float16)fmaf(flow[(b0 + i)*DP + h], aa[h], bb[h]);
  }
  __syncthreads();

  // ---- L1: 32x128 @ 128x256 -> selu -> h1_lds ----
  for (int nt = 0; nt < 4; ++nt){
    const int n = (4*w + nt)*16 + lm;
    const float bias1 = rb1[u*DR + n];
    f16x8 b1[4];
    #pragma unroll
    for (int kc = 0; kc < 4; ++kc)
      b1[kc] = *(const f16x8*)(w1 + n*DP + kc*32 + qd*8);
    #pragma unroll
    for (int mt = 0; mt < 2; ++mt){
      f32x4 acc = {bias1, bias1, bias1, bias1};
      #pragma unroll
      for (int kc = 0; kc < 4; ++kc){
        f16x8 a1 = *(const f16x8*)(&x_lds[(mt*16 + lm)*136 + kc*32 + qd*8]);
        acc = __builtin_amdgcn_mfma_f32_16x16x32_f16(a1, b1[kc], acc, 0, 0, 0);
      }
      #pragma unroll
      for (int r = 0; r < 4; ++r)
        h1_lds[(mt*16 + qd*4 + r)*264 + n] = (_Float16)seluf_(acc[r]);
    }
  }
  __syncthreads();

  // ---- L2: 32x256 @ 256x256 -> selu -> dot w3 (in-wave reduce) ----
  {
    float p[2][4] = {{0.f,0.f,0.f,0.f},{0.f,0.f,0.f,0.f}};
    for (int nt = 0; nt < 4; ++nt){
      const int n = (4*w + nt)*16 + lm;
      const float bias2 = rb2[u*DR + n];
      const float w3l   = rW3[u*DR + n];
      f16x8 b2[8];
      #pragma unroll
      for (int kc = 0; kc < 8; ++kc)
        b2[kc] = *(const f16x8*)(w2 + n*DR + kc*32 + qd*8);
      #pragma unroll
      for (int mt = 0; mt < 2; ++mt){
        f32x4 acc = {bias2, bias2, bias2, bias2};
        #pragma unroll
        for (int kc = 0; kc < 8; ++kc){
          f16x8 a2 = *(const f16x8*)(&h1_lds[(mt*16 + lm)*264 + kc*32 + qd*8]);
          acc = __builtin_amdgcn_mfma_f32_16x16x32_f16(a2, b2[kc], acc, 0, 0, 0);
        }
        #pragma unroll
        for (int r = 0; r < 4; ++r)
          p[mt][r] += seluf_(acc[r]) * w3l;
      }
    }
    #pragma unroll
    for (int mt = 0; mt < 2; ++mt){
      #pragma unroll
      for (int r = 0; r < 4; ++r){
        float v = p[mt][r];
        v += __shfl_xor(v, 1, 64);
        v += __shfl_xor(v, 2, 64);
        v += __shfl_xor(v, 4, 64);
        v += __shfl_xor(v, 8, 64);
        if (lm == 0) y_part[w][mt*16 + qd*4 + r] = v;
      }
    }
  }
  __syncthreads();
  if (tid < 32){
    float y = y_part[0][tid] + y_part[1][tid] + y_part[2][tid] + y_part[3][tid] + rb3[u];
    out[(b0 + tid)*3 + u] = y;
  }
}

extern "C" void kernel_launch(void* const* d_in, const int* in_sizes, int n_in,
                              void* d_out, int out_size, void* d_ws, size_t ws_size,
                              hipStream_t stream){
  const float* demand = (const float*)d_in[0];
  const float* avail  = (const float*)d_in[1];
  const float* capa   = (const float*)d_in[2];
  const float* loss   = (const float*)d_in[3];
  const int*   path   = (const int*)d_in[4];
  const int*   hop    = (const int*)d_in[5];
  const float* wih    = (const float*)d_in[6];
  const float* whh    = (const float*)d_in[7];
  const float* bih    = (const float*)d_in[8];
  const float* bhh    = (const float*)d_in[9];
  const float* gamma  = (const float*)d_in[10];
  const float* beta   = (const float*)d_in[11];
  const float* rW1    = (const float*)d_in[12];
  const float* rb1    = (const float*)d_in[13];
  const float* rW2    = (const float*)d_in[14];
  const float* rb2    = (const float*)d_in[15];
  const float* rW3    = (const float*)d_in[16];
  const float* rb3    = (const float*)d_in[17];
  float* ws  = (float*)d_ws;
  float* out = (float*)d_out;

  prep_all <<<PREP_GRID, 256, 0, stream>>>(path, hop, avail, capa, loss,
                                           whh, rW1, rW2, ws);
  kgru     <<<NJOB, 512, 0, stream>>>(demand, hop, wih, bih, bhh, ws, ws + OFF_FLOW);
  kmlp     <<<dim3(BS/32, 3), 256, 0, stream>>>(ws + OFF_FLOW, ws, gamma, beta,
                                                rb1, rb2, rW3, rb3, out);
}

// Round 7
// 196.915 us; speedup vs baseline: 1.1659x; 1.0485x over previous
//
#include <hip/hip_runtime.h>

// ---------------------------------------------------------------------------
// QoSNet: gather -> 32-step GRU(D=128) -> batchnorm -> 3x SELU MLP readout
// BS=8192, N_LINKS=512, MAX_LEN=32, D_PATH=128, D_READ=256, N_OUT=3.
// R19 = R18 + ONE isolated change:
//   - sig2_/tanh2_ use __builtin_amdgcn_exp2f (raw v_exp_f32, 1 inst) in
//     place of libm exp2f (precise __ocml_exp2_f32: ~12-15 inst fixup per
//     call x 12 calls/wave-step was ~140 of the ~330 VALU insts/wave-step
//     implied by VALUBusy 42% at 2 waves/SIMD).  Inputs are bounded (|x|
//     << 126); overflow saturates to +-inf -> rcp -> exact 0/1 tails.
// R18 kept: feats f16x4 register prefetch (kgru 44.0 -> 42.2 confirmed).
// R16 base: R13 structure + exp2-folded gates + packed f16x4 feats.
// prep_all / kmlp: R16 verbatim.
// Known fixed floor: ~100 us of harness-side timed overhead (43 us of it is
// the 268 MB ws re-poison fill visible in rocprof).  absmax flips between
// 0.0625/0.125 across runs via BN float-atomic order -- not a regression.
// ---------------------------------------------------------------------------

#define BS 8192
#define NL 512
#define ML 32
#define DP 128
#define DR 256
#define NJOB 512             // 16 items per job
#define ST 172               // LDS row stride (f16) for K=160 + pad

// workspace layout (float offsets into d_ws)
#define OFF_SUM    64
#define OFF_SSQ    192
#define OFF_CUR    576
#define OFF_PERM   640                      // BS ints
#define OFF_WHH16  (OFF_PERM + BS)          // 49152 f16  = 24576 fl
#define OFF_W1     (OFF_WHH16 + 24576)      // 98304 f16  = 49152 fl
#define OFF_W2     (OFF_W1 + 49152)         // 196608 f16 = 98304 fl
#define OFF_FEATS  (OFF_W2 + 98304)         // BS*ML f16x4 = 2 MB
#define OFF_FLOW   (OFF_FEATS + BS*ML*4)    // BS*DP fl

// prep_all role partition (256-thr blocks)
#define FEATS_BLOCKS 1024
#define MAX_BLOCKS   256
#define WPREP_BLOCKS 336     // 344064 f16 elements / (256 thr * 4 per thread)
#define SORT_BID     (FEATS_BLOCKS + MAX_BLOCKS + WPREP_BLOCKS)   // 1616
#define PREP_GRID    (SORT_BID + 1)

#define KS (-1.44269504088896340736f)   // -log2(e): sigmoid arg scale
#define KT ( 2.88539008177792681472f)   //  2*log2(e): tanh arg scale

typedef _Float16 f16x8 __attribute__((ext_vector_type(8)));
typedef _Float16 f16x4 __attribute__((ext_vector_type(4)));
typedef float    f32x4 __attribute__((ext_vector_type(4)));

// raw hardware exp2 (v_exp_f32, no libm range fixup)
__device__ __forceinline__ float exp2_raw_(float x){
#if __has_builtin(__builtin_amdgcn_exp2f)
  return __builtin_amdgcn_exp2f(x);
#else
  return exp2f(x);
#endif
}

// gate helpers: args arrive pre-scaled by KS / KT via the weight tables
__device__ __forceinline__ float sig2_(float x){      // x = -log2e * s
  return __builtin_amdgcn_rcpf(1.0f + exp2_raw_(x));
}
__device__ __forceinline__ float tanh2_(float v){     // v = 2*log2e * u
  return fmaf(-2.0f, __builtin_amdgcn_rcpf(1.0f + exp2_raw_(v)), 1.0f);
}
__device__ __forceinline__ float seluf_(float x){
  const float sc = 1.0507009873554805f, al = 1.6732632423543772f;
  return x > 0.0f ? sc*x : sc*al*(__expf(x)-1.0f);
}

// ---------------------------------------------------------------------------
// prep_all: independent roles by blockIdx.x (R16 verbatim).
// ---------------------------------------------------------------------------
__global__ void prep_all(const int* __restrict__ path, const int* __restrict__ hop,
                         const float* __restrict__ avail, const float* __restrict__ capa,
                         const float* __restrict__ loss, const float* __restrict__ whh,
                         const float* __restrict__ rW1, const float* __restrict__ rW2,
                         float* ws){
  const int bid = blockIdx.x;
  const int tid = threadIdx.x;

  if (bid < FEATS_BLOCKS){                       // ---- feats gather (f16x4) ----
    int idx = bid*256 + tid;                     // over BS*ML
    int b = idx >> 5, t = idx & 31;
    f16x4 o = (f16x4)0;
    if (t < hop[b]){
      int l = path[idx];
      float a = avail[b*NL + l];
      float c = capa [b*NL + l];
      o[0] = (_Float16)a;
      o[1] = (_Float16)c;
      o[2] = (_Float16)(a / c);
      o[3] = (_Float16)loss[b*NL + l];
    }
    ((f16x4*)((_Float16*)(ws + OFF_FEATS)))[idx] = o;
  } else if (bid < FEATS_BLOCKS + MAX_BLOCKS){   // ---- global max(capa) ----
    const float4* c4 = (const float4*)capa;
    const int n4 = BS*NL/4;
    float m = 0.0f;
    for (int i = (bid - FEATS_BLOCKS)*256 + tid; i < n4; i += MAX_BLOCKS*256){
      float4 v = c4[i];
      m = fmaxf(m, fmaxf(fmaxf(v.x, v.y), fmaxf(v.z, v.w)));
    }
    #pragma unroll
    for (int o = 32; o > 0; o >>= 1) m = fmaxf(m, __shfl_down(m, o, 64));
    if ((tid & 63) == 0) atomicMax((int*)ws, __float_as_int(m));
  } else if (bid < SORT_BID){                    // ---- f16 weight tables ----
    _Float16* whh16 = (_Float16*)(ws + OFF_WHH16);
    _Float16* w1    = (_Float16*)(ws + OFF_W1);
    _Float16* w2    = (_Float16*)(ws + OFF_W2);
    int base = (bid - FEATS_BLOCKS - MAX_BLOCKS)*1024 + tid*4;
    if (base < 49152){
      // r/z rows (elems < 32768) pre-scaled by -log2e; n rows by 2log2e
      const float s = (base < 32768) ? KS : KT;
      const float4 v = *(const float4*)(whh + base);
      f16x4 o = { (_Float16)(v.x*s), (_Float16)(v.y*s),
                  (_Float16)(v.z*s), (_Float16)(v.w*s) };
      *(f16x4*)(whh16 + base) = o;
    } else if (base < 147456){
      int j = base - 49152; int u = j >> 15; int rem = j & 32767; int n = rem >> 7; int k = rem & 127;
      const float* src = rW1 + u*32768 + k*256 + n;   // k..k+3 same u,n (k%4==0)
      f16x4 o = { (_Float16)src[0], (_Float16)src[256], (_Float16)src[512], (_Float16)src[768] };
      *(f16x4*)(w1 + j) = o;
    } else {
      int j = base - 147456; int u = j >> 16; int rem = j & 65535; int n = rem >> 8; int k = rem & 255;
      const float* src = rW2 + u*65536 + k*256 + n;
      f16x4 o = { (_Float16)src[0], (_Float16)src[256], (_Float16)src[512], (_Float16)src[768] };
      *(f16x4*)(w2 + j) = o;
    }
  } else {                                       // ---- zero ctrl + hop sort ----
    __shared__ int hist[32], start[32];
    for (int i = 64 + tid; i < 640; i += 256) ws[i] = 0.0f;   // SUM/SSQ/CUR
    if (tid < 32) hist[tid] = 0;
    __syncthreads();
    for (int b = tid; b < BS; b += 256) atomicAdd(&hist[32 - hop[b]], 1);  // desc key
    __syncthreads();
    if (tid == 0){ int acc = 0; for (int i = 0; i < 32; ++i){ start[i] = acc; acc += hist[i]; } }
    __syncthreads();
    int* perm = (int*)ws + OFF_PERM;
    for (int b = tid; b < BS; b += 256){
      int pos = atomicAdd(&start[32 - hop[b]], 1);
      perm[pos] = b;
    }
  }
}

// ---------------------------------------------------------------------------
// GRU via MFMA, K=160 augmented A (cols 0..127 h, 128..131 feats, rest 0).
// Single-f16 h: accr/accz get 5 MFMAs, accnh 4, accni 1 per wave per step.
// Block = 512 thr = 8 waves = one 16-item hop-uniform job; wave owns 16 ch.
// Static LPT pairing: blocks i and 767-bid share a CU -> jobs i and 511-i.
// R18: feats f16x4 register prefetch (load t+2, write value from t-1).
// R19: raw v_exp_f32 in the gate epilogue.
// ---------------------------------------------------------------------------
__launch_bounds__(512, 4)
__global__ void kgru(const float* __restrict__ demand, const int* __restrict__ hop,
                     const float* __restrict__ wih, const float* __restrict__ bih,
                     const float* __restrict__ bhh, float* __restrict__ ws,
                     float* __restrict__ flow){
  __shared__ _Float16 hA[2][16*ST];
  const int tid  = threadIdx.x;
  const int w    = tid >> 6;          // 0..7
  const int lane = tid & 63;
  const int lm   = lane & 15;
  const int qd   = lane >> 4;
  const int ch   = w*16 + lm;         // channel owned
  const float inv_maxc = 1.0f / ws[0];
  const int* perm = (const int*)ws + OFF_PERM;
  const f16x4* feats16 = (const f16x4*)((const _Float16*)(ws + OFF_FEATS));
  const _Float16* whh16 = (const _Float16*)(ws + OFF_WHH16);

  const int bid = blockIdx.x;
  const int q = (bid < 256) ? bid : 767 - bid;   // LPT pair on shared CU

  // zero pad/feature cols 128..159, both buffers, before any feature write
  for (int idx = tid; idx < 1024; idx += 512){
    const int buf = idx >> 9;
    const int rem = idx & 511;
    const int m   = rem >> 5;
    const int c   = 128 + (rem & 31);
    hA[buf][m*ST + c] = (_Float16)0.f;
  }

  // B~ fragments (register-resident, pre-scaled via whh16 table)
  f16x8 bfr[5], bfz[5], bfnh[4], bfni;
  #pragma unroll
  for (int kc = 0; kc < 4; ++kc){
    bfr[kc]  = *(const f16x8*)(whh16 + (      ch)*128 + kc*32 + qd*8);
    bfz[kc]  = *(const f16x8*)(whh16 + (128 + ch)*128 + kc*32 + qd*8);
    bfnh[kc] = *(const f16x8*)(whh16 + (256 + ch)*128 + kc*32 + qd*8);
  }
  bfr[4] = (f16x8)0; bfz[4] = (f16x8)0; bfni = (f16x8)0;
  if (qd == 0){
    #pragma unroll
    for (int j = 0; j < 4; ++j){
      float s = (j < 2) ? inv_maxc : 1.0f;
      bfr[4][j] = (_Float16)(wih[(      ch)*32 + 28 + j] * s * KS);
      bfz[4][j] = (_Float16)(wih[(128 + ch)*32 + 28 + j] * s * KS);
      bfni[j]   = (_Float16)(wih[(256 + ch)*32 + 28 + j] * s * KT);
    }
  }
  const float bR  = (bih[ch]     + bhh[ch]    ) * KS;
  const float bZ  = (bih[128+ch] + bhh[128+ch]) * KS;
  const float bNI = bih[256+ch] * KT;
  const float bNH = bhh[256+ch] * KT;

  // job items (per quad: 4 items)
  int it[4], hp[4];
  #pragma unroll
  for (int r = 0; r < 4; ++r){
    it[r] = perm[q*16 + qd*4 + r];
    hp[r] = hop[it[r]];
  }
  int tmax = max(max(hp[0],hp[1]), max(hp[2],hp[3]));
  tmax = max(tmax, __shfl_xor(tmax, 16, 64));
  tmax = max(tmax, __shfl_xor(tmax, 32, 64));

  // feature-writer lanes: 2 per wave (item = w*2 + lane, one f16x4 each)
  const int  fw_i = w*2 + lane;
  const bool fw   = (lane < 2);
  const int  fw_b = fw ? perm[q*16 + fw_i] : 0;

  __syncthreads();   // pad zeroing complete before feature writes

  // init: h0 (cols 0..127) + features(t=0); prime the feats pipeline
  float hprev[4];
  #pragma unroll
  for (int r = 0; r < 4; ++r){
    float h0 = (ch == 127) ? demand[it[r]] * inv_maxc : 0.0f;
    hprev[r] = h0;
    hA[0][(qd*4 + r)*ST + ch] = (_Float16)h0;
  }
  f16x4 fvreg = (f16x4)0;
  if (fw){
    *(f16x4*)(&hA[0][fw_i*ST + 128]) = feats16[fw_b*ML + 0];
    fvreg = feats16[fw_b*ML + 1];     // feats(t=1), retires during step 0
  }
  __syncthreads();

  for (int t = 0; t < tmax; ++t){
    const int cur = t & 1, nxt = cur ^ 1;
    if (fw){
      *(f16x4*)(&hA[nxt][fw_i*ST + 128]) = fvreg;   // feats(t+1), loaded at t-1
      int tn = t + 2; tn = (tn < ML) ? tn : (ML - 1);
      fvreg = feats16[fw_b*ML + tn];                // in flight across this step
    }

    // biases ride in the MFMA C operand (D = A*B + C), pre-scaled
    f32x4 accr  = {bR, bR, bR, bR};
    f32x4 accz  = {bZ, bZ, bZ, bZ};
    f32x4 accnh = {bNH, bNH, bNH, bNH};
    f32x4 accni = {bNI, bNI, bNI, bNI};
    #pragma unroll
    for (int kc = 0; kc < 5; ++kc){
      f16x8 a = *(const f16x8*)(&hA[cur][lm*ST + kc*32 + qd*8]);
      accr = __builtin_amdgcn_mfma_f32_16x16x32_f16(a, bfr[kc], accr, 0, 0, 0);
      accz = __builtin_amdgcn_mfma_f32_16x16x32_f16(a, bfz[kc], accz, 0, 0, 0);
      if (kc < 4)
        accnh = __builtin_amdgcn_mfma_f32_16x16x32_f16(a, bfnh[kc], accnh, 0, 0, 0);
      else
        accni = __builtin_amdgcn_mfma_f32_16x16x32_f16(a, bfni, accni, 0, 0, 0);
    }

    #pragma unroll
    for (int r = 0; r < 4; ++r){
      float rr = sig2_(accr[r]);
      float zz = sig2_(accz[r]);
      float nn = tanh2_(fmaf(rr, accnh[r], accni[r]));
      float hn = fmaf(zz, hprev[r] - nn, nn);          // (1-z)*n + z*h
      if (t < hp[r]) hprev[r] = hn;                    // freeze finished items
      hA[nxt][(qd*4 + r)*ST + ch] = (_Float16)hprev[r];
    }
    __syncthreads();
  }

  float ssum = 0.f, ssq = 0.f;
  #pragma unroll
  for (int r = 0; r < 4; ++r){
    float v = hprev[r];
    flow[it[r]*DP + ch] = v;
    ssum += v;
    ssq  = fmaf(v, v, ssq);
  }
  ssum += __shfl_xor(ssum, 16, 64);  ssum += __shfl_xor(ssum, 32, 64);
  ssq  += __shfl_xor(ssq,  16, 64);  ssq  += __shfl_xor(ssq,  32, 64);
  if (qd == 0){
    atomicAdd(&ws[OFF_SUM + ch], ssum);
    atomicAdd(&ws[OFF_SSQ + ch], ssq);
  }
}

// ---------------------------------------------------------------------------
// BN-finalize + 3-headed MLP via MFMA (R10 verbatim).
// ---------------------------------------------------------------------------
__launch_bounds__(256, 4)
__global__ void kmlp(const float* __restrict__ flow, const float* __restrict__ ws,
                     const float* __restrict__ gamma, const float* __restrict__ beta,
                     const float* __restrict__ rb1, const float* __restrict__ rb2,
                     const float* __restrict__ rW3, const float* __restrict__ rb3,
                     float* __restrict__ out){
  __shared__ _Float16 x_lds[32*136];
  __shared__ _Float16 h1_lds[32*264];
  __shared__ float aa[DP], bb[DP];
  __shared__ float y_part[4][32];
  const int tid  = threadIdx.x;
  const int w    = tid >> 6;
  const int lane = tid & 63;
  const int lm   = lane & 15;
  const int qd   = lane >> 4;
  const int b0   = blockIdx.x * 32;
  const int u    = blockIdx.y;
  const _Float16* w1 = (const _Float16*)(ws + OFF_W1) + u*(DR*DP);
  const _Float16* w2 = (const _Float16*)(ws + OFF_W2) + u*(DR*DR);

  if (tid < DP){                                // BN finalize (redundant/block)
    float m = ws[OFF_SUM + tid] * (1.0f/BS);
    float q = ws[OFF_SSQ + tid] * (1.0f/BS);
    float rstd = rsqrtf(q - m*m + 1e-5f);
    float a = rstd * gamma[tid];
    aa[tid] = a;
    bb[tid] = fmaf(-m, a, beta[tid]);
  }
  __syncthreads();

  for (int idx = tid; idx < 32*DP; idx += 256){
    int i = idx >> 7, h = idx & 127;
    x_lds[i*136 + h] = (_Float16)fmaf(flow[(b0 + i)*DP + h], aa[h], bb[h]);
  }
  __syncthreads();

  // ---- L1: 32x128 @ 128x256 -> selu -> h1_lds ----
  for (int nt = 0; nt < 4; ++nt){
    const int n = (4*w + nt)*16 + lm;
    const float bias1 = rb1[u*DR + n];
    f16x8 b1[4];
    #pragma unroll
    for (int kc = 0; kc < 4; ++kc)
      b1[kc] = *(const f16x8*)(w1 + n*DP + kc*32 + qd*8);
    #pragma unroll
    for (int mt = 0; mt < 2; ++mt){
      f32x4 acc = {bias1, bias1, bias1, bias1};
      #pragma unroll
      for (int kc = 0; kc < 4; ++kc){
        f16x8 a1 = *(const f16x8*)(&x_lds[(mt*16 + lm)*136 + kc*32 + qd*8]);
        acc = __builtin_amdgcn_mfma_f32_16x16x32_f16(a1, b1[kc], acc, 0, 0, 0);
      }
      #pragma unroll
      for (int r = 0; r < 4; ++r)
        h1_lds[(mt*16 + qd*4 + r)*264 + n] = (_Float16)seluf_(acc[r]);
    }
  }
  __syncthreads();

  // ---- L2: 32x256 @ 256x256 -> selu -> dot w3 (in-wave reduce) ----
  {
    float p[2][4] = {{0.f,0.f,0.f,0.f},{0.f,0.f,0.f,0.f}};
    for (int nt = 0; nt < 4; ++nt){
      const int n = (4*w + nt)*16 + lm;
      const float bias2 = rb2[u*DR + n];
      const float w3l   = rW3[u*DR + n];
      f16x8 b2[8];
      #pragma unroll
      for (int kc = 0; kc < 8; ++kc)
        b2[kc] = *(const f16x8*)(w2 + n*DR + kc*32 + qd*8);
      #pragma unroll
      for (int mt = 0; mt < 2; ++mt){
        f32x4 acc = {bias2, bias2, bias2, bias2};
        #pragma unroll
        for (int kc = 0; kc < 8; ++kc){
          f16x8 a2 = *(const f16x8*)(&h1_lds[(mt*16 + lm)*264 + kc*32 + qd*8]);
          acc = __builtin_amdgcn_mfma_f32_16x16x32_f16(a2, b2[kc], acc, 0, 0, 0);
        }
        #pragma unroll
        for (int r = 0; r < 4; ++r)
          p[mt][r] += seluf_(acc[r]) * w3l;
      }
    }
    #pragma unroll
    for (int mt = 0; mt < 2; ++mt){
      #pragma unroll
      for (int r = 0; r < 4; ++r){
        float v = p[mt][r];
        v += __shfl_xor(v, 1, 64);
        v += __shfl_xor(v, 2, 64);
        v += __shfl_xor(v, 4, 64);
        v += __shfl_xor(v, 8, 64);
        if (lm == 0) y_part[w][mt*16 + qd*4 + r] = v;
      }
    }
  }
  __syncthreads();
  if (tid < 32){
    float y = y_part[0][tid] + y_part[1][tid] + y_part[2][tid] + y_part[3][tid] + rb3[u];
    out[(b0 + tid)*3 + u] = y;
  }
}

extern "C" void kernel_launch(void* const* d_in, const int* in_sizes, int n_in,
                              void* d_out, int out_size, void* d_ws, size_t ws_size,
                              hipStream_t stream){
  const float* demand = (const float*)d_in[0];
  const float* avail  = (const float*)d_in[1];
  const float* capa   = (const float*)d_in[2];
  const float* loss   = (const float*)d_in[3];
  const int*   path   = (const int*)d_in[4];
  const int*   hop    = (const int*)d_in[5];
  const float* wih    = (const float*)d_in[6];
  const float* whh    = (const float*)d_in[7];
  const float* bih    = (const float*)d_in[8];
  const float* bhh    = (const float*)d_in[9];
  const float* gamma  = (const float*)d_in[10];
  const float* beta   = (const float*)d_in[11];
  const float* rW1    = (const float*)d_in[12];
  const float* rb1    = (const float*)d_in[13];
  const float* rW2    = (const float*)d_in[14];
  const float* rb2    = (const float*)d_in[15];
  const float* rW3    = (const float*)d_in[16];
  const float* rb3    = (const float*)d_in[17];
  float* ws  = (float*)d_ws;
  float* out = (float*)d_out;

  prep_all <<<PREP_GRID, 256, 0, stream>>>(path, hop, avail, capa, loss,
                                           whh, rW1, rW2, ws);
  kgru     <<<NJOB, 512, 0, stream>>>(demand, hop, wih, bih, bhh, ws, ws + OFF_FLOW);
  kmlp     <<<dim3(BS/32, 3), 256, 0, stream>>>(ws + OFF_FLOW, ws, gamma, beta,
                                                rb1, rb2, rW3, rb3, out);
}